// Round 1
// baseline (117.127 us; speedup 1.0000x reference)
//
#include <hip/hip_runtime.h>
#include <hip/hip_bf16.h>

#define TPB 256

// geometry
#define H 64
#define W 64
#define OYB 16            // output rows per block (stripe)
#define NROWS 28          // staged input rows: oy0-6 .. oy0+21 (rows 1..26 actually used)
#define NDS 42            // ds rows per stripe: j in [2*oy0-5, 2*oy0+36]

#define SIN_STRIDE 72
#define SIN_OFF 5         // input col m stored at SIN_OFF+m ; halo m=-3..-1, 64..66 zero
#define T1_STRIDE 128
#define IR_STRIDE 146     // inter col i2 stored at IR_OFF+i2 ; halo zero
#define IR_OFF 6
#define DS_STRIDE 68

#define REGION1 (NROWS * T1_STRIDE)    // 3584 floats: s_t1 ; s_ds aliases (42*68=2856)
#define REGION2 (NDS * IR_STRIDE)      // 6132 floats: s_ir ; s_in aliases (28*72=2016)
#define LDS_FLOATS (REGION1 + REGION2) // 9716 floats = 38,864 B -> 4 blocks/CU

__global__ __launch_bounds__(TPB, 4)
void afa_fused(const float* __restrict__ in, const float* __restrict__ bias,
               const float* __restrict__ upf, const float* __restrict__ dnf,
               float* __restrict__ out)
{
    __shared__ __align__(16) float lds[LDS_FLOATS];
    float* const s_t1 = lds;            // [NROWS][128]  (W-upsampled rows)
    float* const s_ds = lds;            // [NDS][68]     (aliases t1; live after t1 dead)
    float* const s_in = lds + REGION1;  // [NROWS][72]
    float* const s_ir = lds + REGION1;  // [NDS][146]    (aliases s_in; live after in dead)

    const int tid = threadIdx.x;
    const int blk = blockIdx.x;
    const int plane = blk >> 2;               // n*512 + c
    const int oy0 = (blk & 3) * OYB;          // first output row of stripe
    const int r0 = oy0 - 6;                   // first staged input row
    const int J0 = 2 * oy0 - 5;               // global j of ds row 0

    // filters in registers (uniform loads)
    float g[12], f[12];
#pragma unroll
    for (int k = 0; k < 12; ++k) { g[k] = 2.0f * upf[k]; f[k] = dnf[k]; }
    const float bv = bias[plane & 511];

    // ---- zero all LDS (halos rely on this)
    for (int e = tid; e < LDS_FLOATS / 4; e += TPB)
        ((float4*)lds)[e] = make_float4(0.f, 0.f, 0.f, 0.f);
    __syncthreads();

    // ---- load input rows r0..r0+27 (+bias); invalid rows stay zero
    const float* const pin = in + (size_t)plane * (H * W);
    for (int e = tid; e < NROWS * 16; e += TPB) {
        const int rr = e >> 4;
        const int r = r0 + rr;
        if ((unsigned)r < (unsigned)H) {
            const int c4 = (e & 15) << 2;
            const float4 v = *(const float4*)(pin + r * W + c4);
            float* d = s_in + rr * SIN_STRIDE + SIN_OFF + c4;
            d[0] = v.x + bv; d[1] = v.y + bv; d[2] = v.z + bv; d[3] = v.w + bv;
        }
    }
    __syncthreads();

    // ---- A: horizontal (W) x2 upsample. inter_w[i] = sum_m x[m]*g[5+i-2m]
    // phase-decomposed: i=2u:   taps g11,g9,g7,g5,g3,g1 on x[u-3..u+2]
    //                   i=2u+1: taps g10,g8,g6,g4,g2,g0 on x[u-2..u+3]
    for (int e = tid; e < NROWS * 16; e += TPB) {
        const int rr = e >> 4;
        const int r = r0 + rr;
        if ((unsigned)r >= (unsigned)H) continue;   // t1 row stays zero
        const int ib = (e & 15) << 3;   // 8 consecutive i
        const int u0 = ib >> 1;
        float xr[10];                   // x[u0-3 .. u0+6]
        const float* src = s_in + rr * SIN_STRIDE + (SIN_OFF - 3) + u0;  // even col -> float2 ok
#pragma unroll
        for (int t = 0; t < 5; ++t) {
            const float2 v = *(const float2*)(src + 2 * t);
            xr[2 * t] = v.x; xr[2 * t + 1] = v.y;
        }
        float o[8];
#pragma unroll
        for (int q = 0; q < 4; ++q) {
            o[2*q]   = xr[q]  *g[11] + xr[q+1]*g[9] + xr[q+2]*g[7] + xr[q+3]*g[5] + xr[q+4]*g[3] + xr[q+5]*g[1];
            o[2*q+1] = xr[q+1]*g[10] + xr[q+2]*g[8] + xr[q+3]*g[6] + xr[q+4]*g[4] + xr[q+5]*g[2] + xr[q+6]*g[0];
        }
        float4* dst = (float4*)(s_t1 + rr * T1_STRIDE + ib);
        dst[0] = make_float4(o[0], o[1], o[2], o[3]);
        dst[1] = make_float4(o[4], o[5], o[6], o[7]);
    }
    __syncthreads();

    // ---- B1 halo re-zero: s_ir aliases s_in, so halo cols may hold stale input
    for (int e = tid; e < NDS * 16; e += TPB) {
        const int row = e >> 4, cc2 = e & 15;
        if (cc2 < 12) {
            const int col = (cc2 < 6) ? cc2 : (128 + cc2);  // cols 0..5 and 134..139
            s_ir[row * IR_STRIDE + col] = 0.f;
        }
    }
    // ---- B1: vertical (H) x2 upsample + leaky-relu*sqrt2 -> s_ir (valid j only)
    // j = J0 + jj ; jj even -> phase 1, jj odd -> phase 0. Cache 9 t1 rows per 8-jj block.
    for (int e = tid; e < 64 * 6; e += TPB) {   // 64 i-pairs x 6 jj-blocks
        const int ip = e & 63;
        const int jb = e >> 6;
        const int jj0 = jb << 3;
        const int nq = (jj0 == 40) ? 2 : 8;
        const int i0 = ip << 1;
        const int R = (jj0 >> 1) + 1;           // first t1 rel row needed
        float2 cc[9];
#pragma unroll
        for (int t = 0; t < 9; ++t) {
            int rr2 = R + t; rr2 = rr2 > (NROWS - 1) ? (NROWS - 1) : rr2;  // clamp (unused rows)
            cc[t] = *(const float2*)(s_t1 + rr2 * T1_STRIDE + i0);
        }
        const float sp = 1.41421356237f;
        const float sn = 0.2f * 1.41421356237f;
#pragma unroll
        for (int q = 0; q < 8; ++q) {
            if (q < nq) {
                const int jj = jj0 + q;
                const int j = J0 + jj;
                if ((unsigned)j < 128u) {
                    const int s = q >> 1;
                    float ax, ay;
                    if (q & 1) {   // phase 0: g11,g9,g7,g5,g3,g1
                        ax = cc[s].x*g[11] + cc[s+1].x*g[9] + cc[s+2].x*g[7] + cc[s+3].x*g[5] + cc[s+4].x*g[3] + cc[s+5].x*g[1];
                        ay = cc[s].y*g[11] + cc[s+1].y*g[9] + cc[s+2].y*g[7] + cc[s+3].y*g[5] + cc[s+4].y*g[3] + cc[s+5].y*g[1];
                    } else {       // phase 1: g10,g8,g6,g4,g2,g0
                        ax = cc[s].x*g[10] + cc[s+1].x*g[8] + cc[s+2].x*g[6] + cc[s+3].x*g[4] + cc[s+4].x*g[2] + cc[s+5].x*g[0];
                        ay = cc[s].y*g[10] + cc[s+1].y*g[8] + cc[s+2].y*g[6] + cc[s+3].y*g[4] + cc[s+4].y*g[2] + cc[s+5].y*g[0];
                    }
                    ax = (ax >= 0.f) ? ax * sp : ax * sn;
                    ay = (ay >= 0.f) ? ay * sp : ay * sn;
                    *(float2*)(s_ir + jj * IR_STRIDE + IR_OFF + i0) = make_float2(ax, ay);
                }
            }
        }
    }
    __syncthreads();

    // ---- B2: horizontal (W) /2 downsample. ds[o] = sum_t irow[2o+t-5]*f[11-t]
    for (int e = tid; e < NDS * 16; e += TPB) {   // 672 units
        const int jj = e % NDS;
        const int ob = e / NDS;
        const int o0 = ob << 2;                   // 4 consecutive o
        const int j = J0 + jj;
        float4 dsv = make_float4(0.f, 0.f, 0.f, 0.f);
        if ((unsigned)j < 128u) {
            float wv[18];                         // window cols 2o0+1 .. 2o0+18
            const float* src = s_ir + jj * IR_STRIDE + (2 * o0 + 1);
            wv[0] = src[0];
#pragma unroll
            for (int t = 0; t < 8; ++t) {
                const float2 v = *(const float2*)(src + 1 + 2 * t);
                wv[1 + 2*t] = v.x; wv[2 + 2*t] = v.y;
            }
            wv[17] = src[17];
            float a0 = 0.f, a1 = 0.f, a2 = 0.f, a3 = 0.f;
#pragma unroll
            for (int t = 0; t < 12; ++t) {
                const float ft = f[11 - t];
                a0 += wv[t] * ft; a1 += wv[2 + t] * ft; a2 += wv[4 + t] * ft; a3 += wv[6 + t] * ft;
            }
            dsv = make_float4(a0, a1, a2, a3);
        }
        *(float4*)(s_ds + jj * DS_STRIDE + o0) = dsv;  // out-of-range j -> zeros (true zero-pad)
    }
    __syncthreads();

    // ---- C: vertical (H) /2 downsample + coalesced store
    {
        const int x = tid & 63;
        const int ol0 = (tid >> 6) << 2;          // local oy base: 0,4,8,12
        float colv[18];                           // ds rows 2*ol0 .. 2*ol0+17, column x
#pragma unroll
        for (int t = 0; t < 18; ++t)
            colv[t] = s_ds[(2 * ol0 + t) * DS_STRIDE + x];
        float* po = out + (size_t)plane * (H * W) + (oy0 + ol0) * W + x;
#pragma unroll
        for (int p = 0; p < 4; ++p) {
            float acc = 0.f;
#pragma unroll
            for (int t = 0; t < 12; ++t)
                acc += colv[2 * p + t] * f[11 - t];
            po[p * W] = acc;
        }
    }
}

extern "C" void kernel_launch(void* const* d_in, const int* in_sizes, int n_in,
                              void* d_out, int out_size, void* d_ws, size_t ws_size,
                              hipStream_t stream) {
    const float* in  = (const float*)d_in[0];
    const float* bv  = (const float*)d_in[1];
    const float* upf = (const float*)d_in[2];
    const float* dnf = (const float*)d_in[3];
    float* out = (float*)d_out;
    const int planes = 8 * 512;
    afa_fused<<<planes * 4, TPB, 0, stream>>>(in, bv, upf, dnf, out);
}

// Round 2
// 94.871 us; speedup vs baseline: 1.2346x; 1.2346x over previous
//
#include <hip/hip_runtime.h>
#include <hip/hip_bf16.h>

#define TPB 256

// geometry
#define H 64
#define W 64
#define OYB 16            // output rows per block (stripe)
#define NROWS 26          // staged input rows: r = oy0-5 .. oy0+20 (exactly what H-up consumes)
#define NDS 42            // ds rows per stripe: j in [2*oy0-5, 2*oy0+36]

// LDS strides chosen for bank-conflict-free access (hand-verified per instruction):
#define SIN_STRIDE 74     // == 10 mod 32: A-reads 2 classes -> b64 minimum
#define SIN_OFF 5         // input col m stored at SIN_OFF+m ; halo cols 2..4 / 69..71 zeroed
#define T1_STRIDE 132     // == 4 mod 32: A b128-writes / B1 b128-reads at bank minimum
#define IR_STRIDE 142     // == 6 mod 8: B2 reads (16 consecutive jj per wave) at bank minimum
#define IR_OFF 6          // inter col i2 stored at IR_OFF+i2 ; halo cols 1..5 / 134..138 zeroed
#define DS_STRIDE 68

#define REGION1 (NROWS * T1_STRIDE)    // 3432 floats: s_t1 ; s_ds aliases (42*68=2856)
#define REGION2 (NDS * IR_STRIDE)      // 5964 floats: s_ir ; s_in aliases (26*74=1924)
#define LDS_FLOATS (REGION1 + REGION2) // 9396 floats = 37,584 B -> 4 blocks/CU

static __device__ __forceinline__ float4 mul4(float4 a, float s) {
    return make_float4(a.x * s, a.y * s, a.z * s, a.w * s);
}
static __device__ __forceinline__ float4 fma4(float4 a, float s, float4 c) {
    return make_float4(c.x + a.x * s, c.y + a.y * s, c.z + a.z * s, c.w + a.w * s);
}

__global__ __launch_bounds__(TPB, 4)
void afa_fused(const float* __restrict__ in, const float* __restrict__ bias,
               const float* __restrict__ upf, const float* __restrict__ dnf,
               float* __restrict__ out)
{
    __shared__ __align__(16) float lds[LDS_FLOATS];
    float* const s_t1 = lds;            // [NROWS][132]  (W-upsampled rows)
    float* const s_ds = lds;            // [NDS][68]     (aliases t1; live after t1 dead)
    float* const s_in = lds + REGION1;  // [NROWS][74]
    float* const s_ir = lds + REGION1;  // [NDS][142]    (aliases s_in; live after in dead)

    const int tid = threadIdx.x;
    const int blk = blockIdx.x;
    const int plane = blk >> 2;               // n*512 + c
    const int oy0 = (blk & 3) * OYB;          // first output row of stripe
    const int r0 = oy0 - 5;                   // first staged input row
    const int J0 = 2 * oy0 - 5;               // global j of ds row 0

    float g[12], f[12];
#pragma unroll
    for (int k = 0; k < 12; ++k) { g[k] = 2.0f * upf[k]; f[k] = dnf[k]; }
    const float bv = bias[plane & 511];

    // ---- targeted zeroing (replaces full-LDS blanket zero)
    // s_in halo cols {2,3,4, 69,70,71} for all rows
    if (tid < NROWS * 6) {
        const int row = tid / 6, c = tid - row * 6;
        const int col = (c < 3) ? (2 + c) : (66 + c);
        s_in[row * SIN_STRIDE + col] = 0.f;
    }
    // edge stripes only: zero the 5 t1 rows whose input row is out of range
    if (oy0 == 0 || oy0 == 48) {
        const int rbase = (oy0 == 0) ? 0 : 21;
        if (tid < 5 * (T1_STRIDE / 4)) {          // 5 rows * 33 float4
            const int rr = rbase + tid / 33, c4 = (tid - (tid / 33) * 33) * 4;
            *(float4*)(s_t1 + rr * T1_STRIDE + c4) = make_float4(0.f, 0.f, 0.f, 0.f);
        }
    }

    // ---- load input rows r0..r0+25 (+bias); invalid rows never read
    const float* const pin = in + (size_t)plane * (H * W);
    for (int e = tid; e < NROWS * 16; e += TPB) {
        const int rr = e >> 4;
        const int r = r0 + rr;
        if ((unsigned)r < (unsigned)H) {
            const int c4 = (e & 15) << 2;
            const float4 v = *(const float4*)(pin + r * W + c4);
            float* d = s_in + rr * SIN_STRIDE + SIN_OFF + c4;
            d[0] = v.x + bv; d[1] = v.y + bv; d[2] = v.z + bv; d[3] = v.w + bv;
        }
    }
    __syncthreads();

    // ---- A: horizontal (W) x2 upsample. 208 units, 16 outputs each, single pass.
    // i=2u:   taps g11,g9,g7,g5,g3,g1 on x[u-3..u+2];  i=2u+1: g10..g0 on x[u-2..u+3]
    if (tid < NROWS * 8) {
        const int rr = tid >> 3;
        const int r = r0 + rr;
        if ((unsigned)r < (unsigned)H) {
            const int cb = tid & 7;
            float xr[14];                        // x[8cb-3 .. 8cb+10]
            const float* src = s_in + rr * SIN_STRIDE + (SIN_OFF - 3) + 8 * cb;
#pragma unroll
            for (int t = 0; t < 7; ++t) {
                const float2 v = *(const float2*)(src + 2 * t);
                xr[2 * t] = v.x; xr[2 * t + 1] = v.y;
            }
            float o[16];
#pragma unroll
            for (int q = 0; q < 8; ++q) {
                o[2*q]   = xr[q]  *g[11] + xr[q+1]*g[9] + xr[q+2]*g[7] + xr[q+3]*g[5] + xr[q+4]*g[3] + xr[q+5]*g[1];
                o[2*q+1] = xr[q+1]*g[10] + xr[q+2]*g[8] + xr[q+3]*g[6] + xr[q+4]*g[4] + xr[q+5]*g[2] + xr[q+6]*g[0];
            }
            float* dst = s_t1 + rr * T1_STRIDE + 16 * cb;
#pragma unroll
            for (int k = 0; k < 4; ++k)
                *(float4*)(dst + 4 * k) = make_float4(o[4*k], o[4*k+1], o[4*k+2], o[4*k+3]);
        }
    }
    __syncthreads();

    // ---- s_ir halo cols re-zero (aliases s_in; must follow the A-read barrier)
    for (int e = tid; e < NDS * 10; e += TPB) {
        const int row = e / 10, c = e - row * 10;
        const int col = (c < 5) ? (1 + c) : (129 + c);   // cols 1..5 and 134..138
        s_ir[row * IR_STRIDE + col] = 0.f;
    }

    // ---- B1: vertical (H) x2 upsample + leaky-relu*sqrt2. 224 units = 32 col-quads x 7 row-blocks of 6.
    // jj even: rows jj/2..jj/2+5 taps g10,g8,g6,g4,g2,g0 ; jj odd: rows (jj-1)/2.. taps g11..g1
    if (tid < 224) {
        const int jb = tid >> 5;                 // 0..6
        const int i0 = (tid & 31) * 4;
        const int jj0 = 6 * jb;
        const int R = 3 * jb;                    // rows R..R+7 cover all 6 jj of this block
        float4 cc[8];
#pragma unroll
        for (int t = 0; t < 8; ++t)
            cc[t] = *(const float4*)(s_t1 + (R + t) * T1_STRIDE + i0);
        const float sp = 1.41421356237309515f;
        const float sn = 0.2f * 1.41421356237309515f;
#pragma unroll
        for (int q = 0; q < 6; ++q) {
            const int jj = jj0 + q;
            const int j = J0 + jj;
            if ((unsigned)j < 128u) {
                const int s = q >> 1;            // static: 0,0,1,1,2,2
                float4 a;
                if (q & 1) {
                    a = mul4(cc[s], g[11]);
                    a = fma4(cc[s+1], g[9], a);  a = fma4(cc[s+2], g[7], a);
                    a = fma4(cc[s+3], g[5], a);  a = fma4(cc[s+4], g[3], a);
                    a = fma4(cc[s+5], g[1], a);
                } else {
                    a = mul4(cc[s], g[10]);
                    a = fma4(cc[s+1], g[8], a);  a = fma4(cc[s+2], g[6], a);
                    a = fma4(cc[s+3], g[4], a);  a = fma4(cc[s+4], g[2], a);
                    a = fma4(cc[s+5], g[0], a);
                }
                a.x *= (a.x >= 0.f) ? sp : sn;
                a.y *= (a.y >= 0.f) ? sp : sn;
                a.z *= (a.z >= 0.f) ? sp : sn;
                a.w *= (a.w >= 0.f) ? sp : sn;
                float* dst = s_ir + jj * IR_STRIDE + IR_OFF + i0;
                *(float2*)(dst)     = make_float2(a.x, a.y);
                *(float2*)(dst + 2) = make_float2(a.z, a.w);
            }
        }
    }
    __syncthreads();

    // ---- B2: horizontal (W) /2 downsample. 168 units, 16 outputs each, single pass.
    if (tid < NDS * 4) {
        const int jj = tid >> 2;                 // 16 consecutive jj per wave -> conflict-free
        const int ob = tid & 3;
        const int o0 = 16 * ob;
        const int j = J0 + jj;
        float a[16];
        if ((unsigned)j < 128u) {
            float wv[42];                        // i2 window [2*o0-5 .. 2*o0+36]
            const float* src = s_ir + jj * IR_STRIDE + (IR_OFF - 5) + 2 * o0;  // col 1+32*ob
            wv[0] = src[0];
#pragma unroll
            for (int t = 0; t < 20; ++t) {
                const float2 v = *(const float2*)(src + 1 + 2 * t);
                wv[1 + 2*t] = v.x; wv[2 + 2*t] = v.y;
            }
            wv[41] = src[41];
#pragma unroll
            for (int p = 0; p < 16; ++p) {
                float acc = 0.f;
#pragma unroll
                for (int t = 0; t < 12; ++t)
                    acc += wv[2 * p + t] * f[11 - t];
                a[p] = acc;
            }
        } else {
#pragma unroll
            for (int p = 0; p < 16; ++p) a[p] = 0.f;   // true zero-pad rows
        }
        float* dst = s_ds + jj * DS_STRIDE + o0;
#pragma unroll
        for (int k = 0; k < 4; ++k)
            *(float4*)(dst + 4 * k) = make_float4(a[4*k], a[4*k+1], a[4*k+2], a[4*k+3]);
    }
    __syncthreads();

    // ---- C: vertical (H) /2 downsample + coalesced store
    {
        const int x = tid & 63;
        const int ol0 = (tid >> 6) << 2;          // local oy base: 0,4,8,12
        float colv[18];                           // ds rows 2*ol0 .. 2*ol0+17, column x
#pragma unroll
        for (int t = 0; t < 18; ++t)
            colv[t] = s_ds[(2 * ol0 + t) * DS_STRIDE + x];
        float* po = out + (size_t)plane * (H * W) + (oy0 + ol0) * W + x;
#pragma unroll
        for (int p = 0; p < 4; ++p) {
            float acc = 0.f;
#pragma unroll
            for (int t = 0; t < 12; ++t)
                acc += colv[2 * p + t] * f[11 - t];
            po[p * W] = acc;
        }
    }
}

extern "C" void kernel_launch(void* const* d_in, const int* in_sizes, int n_in,
                              void* d_out, int out_size, void* d_ws, size_t ws_size,
                              hipStream_t stream) {
    const float* in  = (const float*)d_in[0];
    const float* bv  = (const float*)d_in[1];
    const float* upf = (const float*)d_in[2];
    const float* dnf = (const float*)d_in[3];
    float* out = (float*)d_out;
    const int planes = 8 * 512;
    afa_fused<<<planes * 4, TPB, 0, stream>>>(in, bv, upf, dnf, out);
}

// Round 3
// 64.348 us; speedup vs baseline: 1.8202x; 1.4743x over previous
//
#include <hip/hip_runtime.h>

#define TPB 256

// geometry
#define H 64
#define W 64
#define OYB 16            // output rows per block (stripe)

// t1: W-upsampled rows, t1r = 0..23 <-> input row (oy0-4+t1r). 5-tap phases need only these 24.
#define NT1 24
#define T1_STRIDE 132     // ==4 mod 32: b128 read/write at bank minimum (hand-verified)
// ir: H-upsampled + LReLU rows, irr = 0..39 <-> global j = J0+1+irr. Col i2 at word IR_OFF+i2.
#define NIR 40
#define IR_STRIDE 132
#define IR_OFF 4
// t2: H-downsampled rows (16 x 128 + 4-col halos). Col c2 at word T2_OFF+c2.
#define T2_STRIDE 140     // ==12 mod 32: Wdown b128 reads conflict-free
#define T2_OFF 4

#define REGION1 (NT1 * T1_STRIDE)        // 3168 floats: t1 ; t2 (16*140=2240) aliases after B1
#define REGION2 (NIR * IR_STRIDE)        // 5280 floats: ir
#define LDS_FLOATS (REGION1 + REGION2)   // 8448 floats = 33792 B -> 4 blocks/CU

static __device__ __forceinline__ float4 mul4(float4 a, float s) {
    return make_float4(a.x * s, a.y * s, a.z * s, a.w * s);
}
static __device__ __forceinline__ float4 fma4(float4 a, float s, float4 c) {
    return make_float4(c.x + a.x * s, c.y + a.y * s, c.z + a.z * s, c.w + a.w * s);
}
static __device__ __forceinline__ float4 addb(float4 a, float b) {
    return make_float4(a.x + b, a.y + b, a.z + b, a.w + b);
}

__global__ __launch_bounds__(TPB, 4)
void afa_fused(const float* __restrict__ in, const float* __restrict__ bias,
               const float* __restrict__ upf, const float* __restrict__ dnf,
               float* __restrict__ out)
{
    __shared__ __align__(16) float lds[LDS_FLOATS];
    float* const s_t1 = lds;            // [24][132]
    float* const s_t2 = lds;            // [16][140] (aliases t1; live after B1 reads done)
    float* const s_ir = lds + REGION1;  // [40][132]

    const int tid = threadIdx.x;
    const int blk = blockIdx.x;
    const int plane = blk >> 2;               // n*512 + c
    const int oy0 = (blk & 3) * OYB;          // first output row of stripe
    const int J0 = 2 * oy0 - 5;               // global j of ir row jj: j = J0 + jj, jj = irr+1

    // filters (indices 0 and 11 are structurally zero in this op -> 5-tap up phases, 10-tap down)
    float g[11], f[11];
#pragma unroll
    for (int k = 1; k <= 10; ++k) { g[k] = 2.0f * upf[k]; f[k] = dnf[k]; }
    const float bv = bias[plane & 511];

    // ---- edge stripes: zero t1 rows whose input row is out of [0,64). Rows are contiguous.
    if (oy0 == 0 || oy0 == 48) {
        const int rb0 = (oy0 == 0) ? 0 : 20;      // 4 rows: t1r rb0..rb0+3
        for (int w = tid; w < 4 * T1_STRIDE; w += TPB)
            s_t1[rb0 * T1_STRIDE + w] = 0.f;
    }

    // ---- A: global load + bias + horizontal (W) x2 upsample -> t1.  192 units (24 rows x 8).
    // i=2u:   taps g9,g7,g5,g3,g1 on x[u-2..u+2];  i=2u+1: taps g10,g8,g6,g4,g2 on same window.
    if (tid < NT1 * 8) {
        const int ri = tid >> 3;                  // t1r row 0..23
        const int r = oy0 - 4 + ri;               // global input row
        if ((unsigned)r < (unsigned)H) {
            const int cb = tid & 7;               // 8-col group: u0 = 8*cb
            const float4* p4 = (const float4*)(in + (size_t)plane * (H * W) + r * W);
            const float4 z4 = make_float4(0.f, 0.f, 0.f, 0.f);
            // window x[u0-2 .. u0+9]; quads [u0-4..u0-1][u0..][u0+4..][u0+8..u0+11]
            const float4 q0 = (cb == 0) ? z4 : addb(p4[2 * cb - 1], bv);
            const float4 q1 = addb(p4[2 * cb], bv);
            const float4 q2 = addb(p4[2 * cb + 1], bv);
            const float4 q3 = (cb == 7) ? z4 : addb(p4[2 * cb + 2], bv);
            float xr[12];
            xr[0] = q0.z; xr[1] = q0.w;
            xr[2] = q1.x; xr[3] = q1.y; xr[4] = q1.z; xr[5] = q1.w;
            xr[6] = q2.x; xr[7] = q2.y; xr[8] = q2.z; xr[9] = q2.w;
            xr[10] = q3.x; xr[11] = q3.y;
            float o[16];
#pragma unroll
            for (int q = 0; q < 8; ++q) {
                o[2*q]   = xr[q]*g[9]  + xr[q+1]*g[7] + xr[q+2]*g[5] + xr[q+3]*g[3] + xr[q+4]*g[1];
                o[2*q+1] = xr[q]*g[10] + xr[q+1]*g[8] + xr[q+2]*g[6] + xr[q+3]*g[4] + xr[q+4]*g[2];
            }
            float* dst = s_t1 + ri * T1_STRIDE + 16 * cb;
#pragma unroll
            for (int k = 0; k < 4; ++k)
                *(float4*)(dst + 4 * k) = make_float4(o[4*k], o[4*k+1], o[4*k+2], o[4*k+3]);
        }
    }
    __syncthreads();

    // ---- B1: vertical (H) x2 upsample + leaky-relu*sqrt2 -> ir.
    // 256 units: wave u (0..3) x parity P x col-quad c. Each handles 5 jj of one parity.
    // P=1: jj = 10u+2q+1 (odd),  taps g9,g7,g5,g3,g1 ; P=0: jj = 10u+2q+2 (even), taps g10..g2.
    // Both read t1 rows 5u+q .. 5u+q+4  (t1r frame).
    {
        const int u = tid >> 6;                  // wave-uniform
        const int P = (tid >> 5) & 1;
        const int c = tid & 31, i0 = 4 * c;
        float T[5];
#pragma unroll
        for (int k = 0; k < 5; ++k) T[k] = P ? g[9 - 2*k] : g[10 - 2*k];
        float4 cc[9];
#pragma unroll
        for (int t = 0; t < 9; ++t)
            cc[t] = *(const float4*)(s_t1 + (5*u + t) * T1_STRIDE + i0);
        const float sp = 1.41421356237309515f;
        const float sn = 0.2f * 1.41421356237309515f;
#pragma unroll
        for (int q = 0; q < 5; ++q) {
            float4 a = mul4(cc[q], T[0]);
            a = fma4(cc[q+1], T[1], a);
            a = fma4(cc[q+2], T[2], a);
            a = fma4(cc[q+3], T[3], a);
            a = fma4(cc[q+4], T[4], a);
            a.x *= (a.x >= 0.f) ? sp : sn;
            a.y *= (a.y >= 0.f) ? sp : sn;
            a.z *= (a.z >= 0.f) ? sp : sn;
            a.w *= (a.w >= 0.f) ? sp : sn;
            const int jj = 10*u + 2*q + 2 - P;
            const int j = J0 + jj;
            const float4 z4 = make_float4(0.f, 0.f, 0.f, 0.f);
            const float4 wv = ((unsigned)j < 128u) ? a : z4;   // zero-pad rows outside [0,128)
            *(float4*)(s_ir + (jj - 1) * IR_STRIDE + IR_OFF + i0) = wv;
        }
    }
    __syncthreads();

    // ---- Hdown: vertical (H) /2 downsample of ir -> t2 (16 x 128).
    // thread = (col x2 0..127, half h): 8 output rows each; reads ir rows 2*ol+k, k=0..23.
    {
        const int x2 = tid & 127;
        const int ol = (tid >> 7) * 8;
        float colv[24];
#pragma unroll
        for (int k = 0; k < 24; ++k)
            colv[k] = s_ir[(2*ol + k) * IR_STRIDE + IR_OFF + x2];
#pragma unroll
        for (int p = 0; p < 8; ++p) {
            float acc = 0.f;
#pragma unroll
            for (int k = 0; k < 10; ++k)
                acc += colv[2*p + k] * f[10 - k];
            s_t2[(ol + p) * T2_STRIDE + T2_OFF + x2] = acc;
        }
    }
    // t2 halo cols: c2 in {-4..-1, 128..131} -> words {0..3, 132..135}
    if (tid < 128) {
        const int rw = tid >> 3, cz = tid & 7;
        const int col = (cz < 4) ? cz : (128 + cz);
        s_t2[rw * T2_STRIDE + col] = 0.f;
    }
    __syncthreads();

    // ---- Wdown: horizontal (W) /2 downsample of t2 -> global (coalesced float4).
    // unit = (oy 0..15, oxb 0..15): 4 outputs ox = 4*oxb+p; reads 16 words [c2 = 8oxb-4 .. +11].
    {
        const int oy = tid >> 4, oxb = tid & 15;
        const float* base = s_t2 + oy * T2_STRIDE + 8 * oxb;   // word T2_OFF + (8oxb-4)
        float wv[16];
#pragma unroll
        for (int t = 0; t < 4; ++t) {
            const float4 v = *(const float4*)(base + 4 * t);
            wv[4*t] = v.x; wv[4*t+1] = v.y; wv[4*t+2] = v.z; wv[4*t+3] = v.w;
        }
        float o2[4];
#pragma unroll
        for (int p = 0; p < 4; ++p) {
            float acc = 0.f;
#pragma unroll
            for (int k = 0; k < 10; ++k)
                acc += wv[2*p + k] * f[10 - k];
            o2[p] = acc;
        }
        float* po = out + (size_t)plane * (H * W) + (oy0 + oy) * W + 4 * oxb;
        *(float4*)po = make_float4(o2[0], o2[1], o2[2], o2[3]);
    }
}

extern "C" void kernel_launch(void* const* d_in, const int* in_sizes, int n_in,
                              void* d_out, int out_size, void* d_ws, size_t ws_size,
                              hipStream_t stream) {
    const float* in  = (const float*)d_in[0];
    const float* bv  = (const float*)d_in[1];
    const float* upf = (const float*)d_in[2];
    const float* dnf = (const float*)d_in[3];
    float* out = (float*)d_out;
    const int planes = 8 * 512;
    afa_fused<<<planes * 4, TPB, 0, stream>>>(in, bv, upf, dnf, out);
}

// Round 4
// 51.830 us; speedup vs baseline: 2.2598x; 1.2415x over previous
//
#include <hip/hip_runtime.h>

#define TPB 256
#define H 64
#define W 64
#define OYB 16

// t1: W-upsampled rows, t1r = 0..23 <-> input row (oy0-4+t1r)
#define NT1 24
#define T1_STRIDE 132     // ==4 mod 32: b128 write / b64 col-read at bank minimum
// t2: H-downsampled rows (16 x 128 + 4-col halos)
#define T2_STRIDE 140
#define T2_OFF 4
#define T1_FLOATS (NT1 * T1_STRIDE)       // 3168
#define T2_FLOATS (16 * T2_STRIDE)        // 2240
#define LDS_FLOATS (T1_FLOATS + T2_FLOATS) // 5408 floats = 21632 B -> 7 blocks/CU by LDS

typedef float v2f __attribute__((ext_vector_type(2)));

// v_pk_*_f32 (CDNA2+ packed fp32). op_sel[i] = src-i half for LOW result,
// op_sel_hi[i] = src-i half for HIGH result. Plain = [0,..]/[1,..].
#define PKF_ACC(acc,a,b)    asm("v_pk_fma_f32 %0, %1, %2, %0 op_sel:[0,0,0] op_sel_hi:[1,1,1]" : "+v"(acc) : "v"(a), "v"(b))
#define PKF_ACC_A0(acc,a,b) asm("v_pk_fma_f32 %0, %1, %2, %0 op_sel:[0,0,0] op_sel_hi:[0,1,1]" : "+v"(acc) : "v"(a), "v"(b))  // src0 bcast lo
#define PKF_ACC_A1(acc,a,b) asm("v_pk_fma_f32 %0, %1, %2, %0 op_sel:[1,0,0] op_sel_hi:[1,1,1]" : "+v"(acc) : "v"(a), "v"(b))  // src0 bcast hi
#define PKF_ACC_B0(acc,a,b) asm("v_pk_fma_f32 %0, %1, %2, %0 op_sel:[0,0,0] op_sel_hi:[1,0,1]" : "+v"(acc) : "v"(a), "v"(b))  // src1 bcast lo
#define PKF_ACC_B1(acc,a,b) asm("v_pk_fma_f32 %0, %1, %2, %0 op_sel:[0,1,0] op_sel_hi:[1,1,1]" : "+v"(acc) : "v"(a), "v"(b))  // src1 bcast hi
#define PKF_NEW_B0(d,a,b,c) asm("v_pk_fma_f32 %0, %1, %2, %3 op_sel:[0,0,0] op_sel_hi:[1,0,1]" : "=v"(d) : "v"(a), "v"(b), "v"(c))
#define PKF_NEW_B1(d,a,b,c) asm("v_pk_fma_f32 %0, %1, %2, %3 op_sel:[0,1,0] op_sel_hi:[1,1,1]" : "=v"(d) : "v"(a), "v"(b), "v"(c))
#define PKM_A0(d,a,b)       asm("v_pk_mul_f32 %0, %1, %2 op_sel:[0,0] op_sel_hi:[0,1]" : "=v"(d) : "v"(a), "v"(b))            // src0 bcast lo
#define PKM_A1(d,a,b)       asm("v_pk_mul_f32 %0, %1, %2 op_sel:[1,0] op_sel_hi:[1,1]" : "=v"(d) : "v"(a), "v"(b))            // src0 bcast hi
#define PKM_B0(d,a,b)       asm("v_pk_mul_f32 %0, %1, %2 op_sel:[0,0] op_sel_hi:[1,0]" : "=v"(d) : "v"(a), "v"(b))            // src1 bcast lo

__global__ __launch_bounds__(TPB, 6)
void afa_fused(const float* __restrict__ in, const float* __restrict__ bias,
               const float* __restrict__ upf, const float* __restrict__ dnf,
               float* __restrict__ out)
{
    __shared__ __align__(16) float lds[LDS_FLOATS];
    float* const s_t1 = lds;               // [24][132]
    float* const s_t2 = lds + T1_FLOATS;   // [16][140]

    const int tid = threadIdx.x;
    const int blk = blockIdx.x;
    const int plane = blk >> 2;
    const int oy0 = (blk & 3) * OYB;

    // ---- tap setup (one-time).
    // gp[k] = {g[9-2k], g[10-2k]}: W-up/H-up phase-pair taps (g = 2*filt; filt[0]=filt[11]=0).
    // fh[j] = {sqrt2*f[2j+1], sqrt2*f[2j+2]}: H-down taps with the LReLU sqrt2 folded in.
    v2f gp[5], fh[5];
#pragma unroll
    for (int k = 0; k < 5; ++k) {
        gp[k] = (v2f){2.0f * upf[9 - 2*k], 2.0f * upf[10 - 2*k]};
        fh[k] = (v2f){1.41421356237309515f * dnf[2*k + 1], 1.41421356237309515f * dnf[2*k + 2]};
    }
    float fd[11];
#pragma unroll
    for (int k = 1; k <= 10; ++k) fd[k] = dnf[k];          // W-down taps (unscaled)
    const float bv = bias[plane & 511];
    const v2f b2  = (v2f){bv, bv};
    const v2f cst = (v2f){0.6f, 0.4f};                      // lrelu: 0.6x + 0.4|x| (sqrt2 folded into fh)
    const v2f z2  = (v2f){0.f, 0.f};

    // ---- edge stripes: zero the 4 t1 rows whose input row is outside [0,64)
    if (oy0 == 0 || oy0 == 48) {
        const int rb0 = (oy0 == 0) ? 0 : 20;
        for (int w = tid; w < 4 * T1_STRIDE; w += TPB)
            s_t1[rb0 * T1_STRIDE + w] = 0.f;
    }

    // ---- A: global load + horizontal (W) x2 upsample -> t1 (bias commutes past linear convs).
    // po[q] = {o[2q], o[2q+1]} = sum_k xr[q+k] * gp[k]  (window broadcast via op_sel)
    if (tid < NT1 * 8) {
        const int ri = tid >> 3;
        const int r = oy0 - 4 + ri;
        if ((unsigned)r < (unsigned)H) {
            const int cb = tid & 7;
            const float4* p4 = (const float4*)(in + (size_t)plane * (H * W) + r * W);
            const float4 z4 = make_float4(0.f, 0.f, 0.f, 0.f);
            const float4 q0 = (cb == 0) ? z4 : p4[2 * cb - 1];
            const float4 q1 = p4[2 * cb];
            const float4 q2 = p4[2 * cb + 1];
            const float4 q3 = (cb == 7) ? z4 : p4[2 * cb + 2];
            v2f wr2[6];                      // window x[8cb-2 .. 8cb+9] as 6 pairs
            wr2[0] = (v2f){q0.z, q0.w};
            wr2[1] = (v2f){q1.x, q1.y};  wr2[2] = (v2f){q1.z, q1.w};
            wr2[3] = (v2f){q2.x, q2.y};  wr2[4] = (v2f){q2.z, q2.w};
            wr2[5] = (v2f){q3.x, q3.y};
            v2f po[8];
#pragma unroll
            for (int q = 0; q < 8; ++q) {
                if (q & 1) { PKM_A1(po[q], wr2[q >> 1], gp[0]); }
                else       { PKM_A0(po[q], wr2[q >> 1], gp[0]); }
#pragma unroll
                for (int k = 1; k < 5; ++k) {
                    if ((q + k) & 1) { PKF_ACC_A1(po[q], wr2[(q + k) >> 1], gp[k]); }
                    else             { PKF_ACC_A0(po[q], wr2[(q + k) >> 1], gp[k]); }
                }
            }
            float* dst = s_t1 + ri * T1_STRIDE + 16 * cb;
#pragma unroll
            for (int k = 0; k < 4; ++k)
                *(float4*)(dst + 4 * k) = make_float4(po[2*k][0], po[2*k][1], po[2*k+1][0], po[2*k+1][1]);
        }
    }
    __syncthreads();

    // ---- fusedV: per column-pair, H-up + bias + LReLU + H-down entirely in registers.
    // thread: cols (2c, 2c+1), quarter q4 -> t2 rows 4q4..4q4+3; reads t1 rows 4q4..4q4+11.
    {
        const int c = tid & 63;
        const int q4 = tid >> 6;                  // wave-uniform
        const bool mlo = (oy0 == 0)  && (q4 == 0);   // j = s-4 < 0  for s<=3
        const bool mhi = (oy0 == 48) && (q4 == 3);   // j = 116+s >= 128 for s>=12
        v2f cc[12];
#pragma unroll
        for (int t = 0; t < 12; ++t)
            cc[t] = *(const v2f*)(s_t1 + (4 * q4 + t) * T1_STRIDE + 2 * c);
        v2f acc[4] = {z2, z2, z2, z2};
#pragma unroll
        for (int t = 0; t < 8; ++t) {
            // ir rows s=2t (odd jj, taps gp[k].x) and s=2t+1 (even jj, taps gp[k].y), window cc[t..t+4]
            v2f ta, tb;
            PKF_NEW_B0(ta, cc[t], gp[0], b2);
            PKF_NEW_B1(tb, cc[t], gp[0], b2);
#pragma unroll
            for (int k = 1; k < 5; ++k) {
                PKF_ACC_B0(ta, cc[t + k], gp[k]);
                PKF_ACC_B1(tb, cc[t + k], gp[k]);
            }
            if (mlo && t < 2)  { ta = z2; tb = z2; }    // zero-pad rows outside the 128-row frame
            if (mhi && t >= 6) { ta = z2; tb = z2; }
            // lrelu (unscaled): r = 0.6x + 0.4|x|
            v2f ra, aa, rb, ab;
            PKM_B0(ra, ta, cst);
            aa.x = __builtin_fabsf(ta.x); aa.y = __builtin_fabsf(ta.y);
            PKF_ACC_B1(ra, aa, cst);
            PKM_B0(rb, tb, cst);
            ab.x = __builtin_fabsf(tb.x); ab.y = __builtin_fabsf(tb.y);
            PKF_ACC_B1(rb, ab, cst);
            // H-down accumulate: tap index 10-(s-2p); even s -> fh[4-(t-p)].y, odd s -> .x
#pragma unroll
            for (int p = 0; p < 4; ++p) {
                if (p >= t - 4 && p <= t) {
                    PKF_ACC_B1(acc[p], ra, fh[4 - (t - p)]);
                    PKF_ACC_B0(acc[p], rb, fh[4 - (t - p)]);
                }
            }
        }
#pragma unroll
        for (int p = 0; p < 4; ++p)
            *(v2f*)(s_t2 + (4 * q4 + p) * T2_STRIDE + T2_OFF + 2 * c) = acc[p];
    }
    // t2 halo cols: c2 in {-4..-1, 128..131} -> words {0..3, 132..135}
    if (tid < 128) {
        const int rw = tid >> 3, cz = tid & 7;
        const int col = (cz < 4) ? cz : (128 + cz);
        s_t2[rw * T2_STRIDE + col] = 0.f;
    }
    __syncthreads();

    // ---- Wdown: horizontal (W) /2 downsample of t2 -> global (coalesced float4).
    {
        const int oy = tid >> 4, oxb = tid & 15;
        const float* base = s_t2 + oy * T2_STRIDE + 8 * oxb;   // word T2_OFF + (8oxb-4)
        float wv[16];
#pragma unroll
        for (int t = 0; t < 4; ++t) {
            const float4 v = *(const float4*)(base + 4 * t);
            wv[4*t] = v.x; wv[4*t+1] = v.y; wv[4*t+2] = v.z; wv[4*t+3] = v.w;
        }
        float o2[4];
#pragma unroll
        for (int p = 0; p < 4; ++p) {
            float acc = 0.f;
#pragma unroll
            for (int k = 0; k < 10; ++k)
                acc += wv[2*p + k] * fd[10 - k];
            o2[p] = acc;
        }
        float* po = out + (size_t)plane * (H * W) + (oy0 + oy) * W + 4 * oxb;
        *(float4*)po = make_float4(o2[0], o2[1], o2[2], o2[3]);
    }
}

extern "C" void kernel_launch(void* const* d_in, const int* in_sizes, int n_in,
                              void* d_out, int out_size, void* d_ws, size_t ws_size,
                              hipStream_t stream) {
    const float* in  = (const float*)d_in[0];
    const float* bv  = (const float*)d_in[1];
    const float* upf = (const float*)d_in[2];
    const float* dnf = (const float*)d_in[3];
    float* out = (float*)d_out;
    const int planes = 8 * 512;
    afa_fused<<<planes * 4, TPB, 0, stream>>>(in, bv, upf, dnf, out);
}